// Round 1
// 666.656 us; speedup vs baseline: 1.0037x; 1.0037x over previous
//
#include <hip/hip_runtime.h>

// src [B,C,D,H,W] fp32, v [B,2,D,H,W] fp32, out [B,C,D,H,W] fp32
#define NB 8
#define NC 4
#define ND 32
#define NH 256
#define NW 256

// Tile: 8 rows x 256 cols per block (256 threads; thread = 4 cols x 2 rows).
// XCD-contiguous block remap so vertically-adjacent tiles share one XCD's L2
// (per-XCD L2s are private; default round-robin dispatch was fetching each
// src line from ~3 different XCDs -> 2.8x src over-fetch).
__global__ __launch_bounds__(256) void st_warp_kernel(const float* __restrict__ src,
                                                      const float* __restrict__ v,
                                                      float* __restrict__ out) {
    const int HW  = NH * NW;              // 65536
    const int DHW = ND * HW;              // 2097152
    const int ROWBLKS = NH / 8;           // 32 row-tiles per (b,d) slice
    const int NBLK  = NB * ND * ROWBLKS;  // 8192 blocks
    const int CHUNK = NBLK / 8;           // 1024 blocks per XCD (evenly divides -> bijective)

    int p = blockIdx.x;
    int l = (p & 7) * CHUNK + (p >> 3);   // XCD-contiguous logical block id

    int rowblk = l & (ROWBLKS - 1);
    int bd     = l >> 5;                  // b*ND + d
    int b      = bd >> 5;                 // ND = 32
    int dHW    = (bd & (ND - 1)) * HW;

    int tid = threadIdx.x;
    int x   = (tid & 63) << 2;                 // 4 px horizontally (float4)
    int yb  = rowblk * 8 + ((tid >> 6) << 1);  // 2 rows vertically

    const float* vb = v   + b * 2  * DHW + dHW;
    const float* sb = src + b * NC * DHW + dHW;
    float*       ob = out + b * NC * DHW + dHW;

    // reference: ix = (x+vx)*(W-1)/(H-1), iy = y+vy  (here sx == 1.0f, kept exact)
    const float sx = (float)(NW - 1) / (float)(NH - 1);

#pragma unroll
    for (int r = 0; r < 2; ++r) {
        int yy     = yb + r;
        int rowoff = (yy << 8) + x;

        float4 vx4 = *reinterpret_cast<const float4*>(vb + rowoff);
        float4 vy4 = *reinterpret_cast<const float4*>(vb + DHW + rowoff);

        float vxa[4] = {vx4.x, vx4.y, vx4.z, vx4.w};
        float vya[4] = {vy4.x, vy4.y, vy4.z, vy4.w};

        float w00[4], w10[4], w01[4], w11[4];
        int   i00[4], i10[4], i01[4], i11[4];

#pragma unroll
        for (int j = 0; j < 4; ++j) {
            float fx  = ((float)(x + j) + vxa[j]) * sx;
            float fy  = (float)yy + vya[j];
            float x0f = floorf(fx), y0f = floorf(fy);
            float fx1 = fx - x0f, fx0 = 1.0f - fx1;
            float fy1 = fy - y0f, fy0 = 1.0f - fy1;
            int x0 = (int)x0f, y0 = (int)y0f;
            int x1 = x0 + 1,   y1 = y0 + 1;

            bool vx0 = (x0 >= 0) & (x0 <= NW - 1);
            bool vx1 = (x1 >= 0) & (x1 <= NW - 1);
            bool vy0 = (y0 >= 0) & (y0 <= NH - 1);
            bool vy1 = (y1 >= 0) & (y1 <= NH - 1);

            int x0c = min(max(x0, 0), NW - 1);
            int x1c = min(max(x1, 0), NW - 1);
            int r0  = min(max(y0, 0), NH - 1) << 8;
            int r1  = min(max(y1, 0), NH - 1) << 8;

            w00[j] = (vx0 && vy0) ? fx0 * fy0 : 0.0f;
            w10[j] = (vx1 && vy0) ? fx1 * fy0 : 0.0f;
            w01[j] = (vx0 && vy1) ? fx0 * fy1 : 0.0f;
            w11[j] = (vx1 && vy1) ? fx1 * fy1 : 0.0f;
            i00[j] = r0 + x0c;
            i10[j] = r0 + x1c;
            i01[j] = r1 + x0c;
            i11[j] = r1 + x1c;
        }

#pragma unroll
        for (int c = 0; c < NC; ++c) {
            const float* pc = sb + c * DHW;
            float acc[4];
#pragma unroll
            for (int j = 0; j < 4; ++j) {
                acc[j] = pc[i00[j]] * w00[j] + pc[i10[j]] * w10[j]
                       + pc[i01[j]] * w01[j] + pc[i11[j]] * w11[j];
            }
            *reinterpret_cast<float4*>(ob + c * DHW + rowoff) =
                make_float4(acc[0], acc[1], acc[2], acc[3]);
        }
    }
}

extern "C" void kernel_launch(void* const* d_in, const int* in_sizes, int n_in,
                              void* d_out, int out_size, void* d_ws, size_t ws_size,
                              hipStream_t stream) {
    const float* src = (const float*)d_in[0];
    const float* v   = (const float*)d_in[1];
    float* out       = (float*)d_out;

    int nblk = NB * ND * (NH / 8);        // 8192 blocks x 256 threads, 8 px/thread
    dim3 grid(nblk), block(256);
    st_warp_kernel<<<grid, block, 0, stream>>>(src, v, out);
}

// Round 2
// 533.120 us; speedup vs baseline: 1.2552x; 1.2505x over previous
//
#include <hip/hip_runtime.h>

// src [B,C,D,H,W] fp32, v [B,2,D,H,W] fp32, out [B,C,D,H,W] fp32
#define NB 8
#define NC 4
#define ND 32
#define NH 256
#define NW 256

#define ROWS 8                     // output rows per block
#define HALO 6                     // staged halo; P(|vy|>6) ~ 2e-9 -> fallback ~never
#define NSTAGE (ROWS + 2 * HALO)   // 20 staged rows = 20 KB LDS

// Block = 256 threads = 1 column each, 8 rows x 256 cols tile.
// Phase A: compute bilinear indices/weights once (reused for all 4 channels).
// Phase B: per channel { stage 20 rows to LDS coalesced; gather from LDS }.
// Divergent gathers hit LDS (bank = x%32, consecutive lanes -> conflict-free)
// instead of the TA/L1 path that was paying ~1 cyc per distinct 64B line.
__global__ __launch_bounds__(256) void st_lds_kernel(const float* __restrict__ src,
                                                     const float* __restrict__ v,
                                                     float* __restrict__ out) {
    const int HW  = NH * NW;                  // 65536
    const int DHW = ND * HW;                  // 2097152
    const int ROWBLKS = NH / ROWS;            // 32
    const int NBLK  = NB * ND * ROWBLKS;      // 8192
    const int CHUNK = NBLK / 8;               // 1024 (divides evenly -> bijective)

    __shared__ float tile[NSTAGE * NW];       // 20 KB

    int p = blockIdx.x;
    int l = (p & 7) * CHUNK + (p >> 3);       // XCD-contiguous logical block id

    int rowblk = l & (ROWBLKS - 1);
    int bd     = l >> 5;                      // b*ND + d
    int b      = bd >> 5;
    int dHW    = (bd & (ND - 1)) * HW;
    int row0   = rowblk * ROWS;
    int base   = row0 - HALO;                 // global row of LDS slot 0

    const float* vb = v   + b * 2  * DHW + dHW;
    const float* sb = src + b * NC * DHW + dHW;
    float*       ob = out + b * NC * DHW + dHW;

    int t    = threadIdx.x;                   // column
    int wave = t >> 6;
    int lane = t & 63;

    const float sx = (float)(NW - 1) / (float)(NH - 1);   // == 1.0f here, kept exact

    int   xpack[ROWS], spack[ROWS];
    float w00[ROWS], w10[ROWS], w01[ROWS], w11[ROWS];

#pragma unroll
    for (int r = 0; r < ROWS; ++r) {
        int yy = row0 + r;
        float vx = vb[yy * NW + t];
        float vy = vb[DHW + yy * NW + t];
        float fx = ((float)t + vx) * sx;
        float fy = (float)yy + vy;
        float x0f = floorf(fx), y0f = floorf(fy);
        float fx1 = fx - x0f, fx0 = 1.0f - fx1;
        float fy1 = fy - y0f, fy0 = 1.0f - fy1;
        int x0 = (int)x0f, y0 = (int)y0f;
        int x1 = x0 + 1,   y1 = y0 + 1;

        bool vbx0 = (x0 >= 0) & (x0 <= NW - 1);
        bool vbx1 = (x1 >= 0) & (x1 <= NW - 1);
        bool vby0 = (y0 >= 0) & (y0 <= NH - 1);
        bool vby1 = (y1 >= 0) & (y1 <= NH - 1);

        int x0c = min(max(x0, 0), NW - 1);
        int x1c = min(max(x1, 0), NW - 1);
        int y0c = min(max(y0, 0), NH - 1);
        int y1c = min(max(y1, 0), NH - 1);

        w00[r] = (vbx0 && vby0) ? fx0 * fy0 : 0.0f;
        w10[r] = (vbx1 && vby0) ? fx1 * fy0 : 0.0f;
        w01[r] = (vbx0 && vby1) ? fx0 * fy1 : 0.0f;
        w11[r] = (vbx1 && vby1) ? fx1 * fy1 : 0.0f;

        int s0 = y0c - base;
        int s1 = y1c - base;
        int fb = (((unsigned)s0 >= NSTAGE) | ((unsigned)s1 >= NSTAGE)) ? 1 : 0;
        if (fb) { s0 = 0; s1 = 0; }           // keep LDS access in-bounds; unused
        xpack[r] = x0c | (x1c << 16);
        spack[r] = s0 | (s1 << 8) | (fb << 16);
    }

    for (int c = 0; c < NC; ++c) {
        const float* sc = sb + c * DHW;
        if (c) __syncthreads();               // protect previous channel's reads
#pragma unroll
        for (int k = 0; k < NSTAGE / 4; ++k) {
            int srow = k * 4 + wave;          // 0..19, one full row per wave
            int grow = min(max(base + srow, 0), NH - 1);
            float4 val = *reinterpret_cast<const float4*>(sc + grow * NW + lane * 4);
            *reinterpret_cast<float4*>(tile + srow * NW + lane * 4) = val;
        }
        __syncthreads();

        float* oc = ob + c * DHW + row0 * NW + t;
#pragma unroll
        for (int r = 0; r < ROWS; ++r) {
            int x0c = xpack[r] & 0xffff;
            int x1c = xpack[r] >> 16;
            int s0  = spack[r] & 0xff;
            int s1  = (spack[r] >> 8) & 0xff;
            const float* t0 = tile + s0 * NW;
            const float* t1 = tile + s1 * NW;
            float val = t0[x0c] * w00[r] + t0[x1c] * w10[r]
                      + t1[x0c] * w01[r] + t1[x1c] * w11[r];
            if (spack[r] >> 16) {
                // rare fallback: sampled rows fell outside the staged halo
                int yy = row0 + r;
                float vy = vb[DHW + yy * NW + t];
                int y0  = (int)floorf((float)yy + vy);
                int y0c = min(max(y0, 0), NH - 1);
                int y1c = min(max(y0 + 1, 0), NH - 1);
                val = sc[y0c * NW + x0c] * w00[r] + sc[y0c * NW + x1c] * w10[r]
                    + sc[y1c * NW + x0c] * w01[r] + sc[y1c * NW + x1c] * w11[r];
            }
            oc[r * NW] = val;
        }
    }
}

extern "C" void kernel_launch(void* const* d_in, const int* in_sizes, int n_in,
                              void* d_out, int out_size, void* d_ws, size_t ws_size,
                              hipStream_t stream) {
    const float* src = (const float*)d_in[0];
    const float* v   = (const float*)d_in[1];
    float* out       = (float*)d_out;

    int nblk = NB * ND * (NH / ROWS);         // 8192 blocks
    dim3 grid(nblk), block(256);
    st_lds_kernel<<<grid, block, 0, stream>>>(src, v, out);
}